// Round 2
// baseline (88.908 us; speedup 1.0000x reference)
//
#include <hip/hip_runtime.h>
#include <stdint.h>
#include <math.h>

#define B_    4
#define H_    192
#define W_    192
#define HW    (H_*W_)            // 36864
#define NPIX  (B_*HW)            // 147456
#define C_V   10
#define C_F   64
#define C_D   16
#define C_ALL (C_V+C_F+C_D)      // 90
#define HBINS 32768              // keys always have bit31 set -> real bin = 32768 + hb
#define CAP   2048               // bin-b* list capacity (expected ~80-150 items)

// ---- workspace layout (bytes) ----
#define OFF_HIST 0u                                   // 4*HBINS*4 = 512 KB (zeroed by k_zero)
#define OFF_KEY  (4u*HBINS*4u)                        // NPIX*4
#define OFF_G    (OFF_KEY + (uint32_t)NPIX*4u)        // NPIX   (packed bytes)
#define OFF_SELX (OFF_G + (uint32_t)NPIX)             // NPIX   (zeroed by k_prep)
#define OFF_HL   (OFF_SELX + (uint32_t)NPIX)          // 4 uints: per-batch selection threshold

__device__ __forceinline__ uint32_t costOf(uint32_t g) {
    return g == 0u ? 10u : (g == 1u ? 5u : 2u);
}

// budget_per_sample = float32(budget / B); usage,c are exact ints ->
// usage+c <= bps  <=>  usage+c <= floor(bps)
__device__ __forceinline__ uint32_t budgetInt(const int* bptr) {
    double bps = (double)bptr[0] / (double)B_;
    float f = (float)bps;
    return (uint32_t)floorf(f);
}

// K0: zero the histogram (512 KB) — replaces the 40us rocclr fill
__global__ void k_zero(uint4* __restrict__ hist4) {
    int i = blockIdx.x * blockDim.x + threadIdx.x;   // [0, 32768)
    hist4[i] = make_uint4(0u, 0u, 0u, 0u);
}

// K1: per-pixel best utility / group / sortable key, zero selx, cost histogram.
// 4 pixels per thread (12 floats = 3x float4, 48B-aligned groups).
__global__ void k_prep(const float* __restrict__ util, uint4* __restrict__ key4,
                       uint32_t* __restrict__ g4, uint32_t* __restrict__ selx4,
                       uint32_t* __restrict__ hist) {
    int t = blockIdx.x * blockDim.x + threadIdx.x;   // [0, NPIX/4)
    if (t >= NPIX / 4) return;
    const float4* u4 = (const float4*)util + (size_t)t * 3;
    float4 a = u4[0], b4 = u4[1], c4 = u4[2];
    float u[4][3] = { {a.x, a.y, a.z}, {a.w, b4.x, b4.y},
                      {b4.z, b4.w, c4.x}, {c4.y, c4.z, c4.w} };
    uint32_t kk[4]; uint32_t gpack = 0;
    #pragma unroll
    for (int p = 0; p < 4; ++p) {
        float best = u[p][0]; uint32_t g = 0;
        if (u[p][1] > best) { best = u[p][1]; g = 1; }   // strict > = first max (jnp.argmax)
        if (u[p][2] > best) { best = u[p][2]; g = 2; }
        kk[p] = (best > 0.0f) ? (__float_as_uint(best) | 0x80000000u) : 0u;
        gpack |= g << (8 * p);
    }
    key4[t] = make_uint4(kk[0], kk[1], kk[2], kk[3]);
    g4[t] = gpack;
    selx4[t] = 0u;
    int b = (t * 4) / HW;                     // HW % 4 == 0: group never crosses batch
    #pragma unroll
    for (int p = 0; p < 4; ++p)
        if (kk[p])
            atomicAdd(&hist[(size_t)b * HBINS + ((kk[p] >> 16) & 32767u)],
                      costOf((gpack >> (8 * p)) & 3u));
}

// K2 (merged cutoff+collect+scan): per batch — descending cumsum over hist ->
// crossing bin b*; collect bin-b* items; LDS rank-sort; serial greedy replay;
// then <=4 tail picks below b* via max-reduction rounds (all L2-hot).
__global__ __launch_bounds__(1024) void k_select(const uint32_t* __restrict__ key,
                                                 const uint8_t* __restrict__ g,
                                                 const uint32_t* __restrict__ hist,
                                                 const int* __restrict__ budget_ptr,
                                                 uint8_t* __restrict__ selx,
                                                 uint32_t* __restrict__ hl_out) {
    int b = blockIdx.x;
    int t = threadIdx.x;
    uint32_t budget = budgetInt(budget_ptr);

    __shared__ uint32_t scan[1024];
    __shared__ uint64_t e[CAP];
    __shared__ uint64_t s[CAP];
    __shared__ uint64_t red[1024];
    __shared__ uint32_t f_b2, f_usage, sh_n, sh_r, sh_poskey, sh_pospix;

    if (t == 0) { f_b2 = 0xFFFFFFFFu; f_usage = 0u; sh_n = 0u; }
    __syncthreads();

    // --- Phase A: find crossing bin ---
    const uint32_t* hb = hist + (size_t)b * HBINS;
    int hi = 32767 - 32 * t;                 // chunk t covers bins hi .. hi-31 (descending)
    uint32_t cs = 0;
    #pragma unroll 4
    for (int j = 0; j < 32; ++j) cs += hb[hi - j];
    scan[t] = cs;
    __syncthreads();
    for (int off = 1; off < 1024; off <<= 1) {   // Hillis-Steele inclusive scan
        uint32_t v = (t >= off) ? scan[t - off] : 0u;
        __syncthreads();
        scan[t] += v;
        __syncthreads();
    }
    uint32_t incl = scan[t], excl = incl - cs;
    if (excl <= budget && incl > budget) {       // first crossing lives in this chunk
        uint32_t cum = excl;
        for (int j = 0; j < 32; ++j) {
            uint32_t hv = hb[hi - j];
            if (cum + hv > budget) { f_b2 = (uint32_t)(hi - j); f_usage = cum; break; }
            cum += hv;
        }
    }
    __syncthreads();
    uint32_t b2 = f_b2;
    if (t == 0) {
        uint32_t hl;
        if (b2 == 0xFFFFFFFFu)           hl = 1u;            // no crossing: all valid selected
        else {
            uint32_t bs = b2 + 32768u;
            hl = (bs >= 65535u) ? 0xFFFFFFFFu : ((bs + 1u) << 16);
        }
        hl_out[b] = hl;
    }
    if (b2 == 0xFFFFFFFFu) return;               // uniform across block

    // --- Phase B: collect bin-b* items ---
    const uint32_t* kb = key + (size_t)b * HW;
    const uint8_t*  gb = g   + (size_t)b * HW;
    for (int i = t; i < HW; i += 1024) {
        uint32_t k = kb[i];
        if (k && ((k >> 16) & 32767u) == b2) {
            uint32_t idx = atomicAdd(&sh_n, 1u);
            if (idx < CAP)   // asc key: (~k, pix) -> utility desc, flat idx asc (stable ties)
                e[idx] = ((uint64_t)(~k) << 32) | ((uint64_t)i << 2) | (uint64_t)gb[i];
        }
    }
    __syncthreads();
    int n = (int)(sh_n < (uint32_t)CAP ? sh_n : (uint32_t)CAP);

    // --- rank sort (composite keys distinct: pix unique) ---
    for (int i = t; i < n; i += 1024) {
        uint64_t ei = e[i];
        int rk = 0;
        for (int j = 0; j < n; ++j) rk += (e[j] < ei);
        s[rk] = ei;
    }
    __syncthreads();

    // --- serial greedy within bin b* ---
    if (t == 0) {
        uint32_t usage = f_usage;
        uint8_t* sx = selx + (size_t)b * HW;
        for (int i = 0; i < n; ++i) {
            uint64_t ei = s[i];
            uint32_t c = costOf((uint32_t)(ei & 3u));
            if (usage + c <= budget) { usage += c; sx[(ei >> 2) & 0xFFFFu] = 1; }
        }
        sh_r = budget - usage;                   // provably <= 9
        sh_poskey = (b2 + 32768u) << 16;         // resume just after bin b*
        sh_pospix = 0xFFFFFFFFu;
    }
    __syncthreads();

    // --- tail: next item in sort order with cost <= r; at most 4 picks ---
    for (int round = 0; round < 8; ++round) {
        uint32_t r = sh_r;
        if (r < 2u) break;
        uint32_t pkey = sh_poskey, ppix = sh_pospix;
        uint64_t best = 0;
        for (int i = t; i < HW; i += 1024) {
            uint32_t k = kb[i];
            if (!k) continue;
            if (!(k < pkey || (k == pkey && (uint32_t)i > ppix))) continue;
            if (costOf(gb[i]) > r) continue;
            uint64_t m = ((uint64_t)k << 16) | (uint64_t)(65535u - (uint32_t)i);
            if (m > best) best = m;              // max key, then min pix
        }
        red[t] = best;
        __syncthreads();
        for (int off = 512; off > 0; off >>= 1) {
            if (t < off) {
                uint64_t o = red[t + off];
                if (o > red[t]) red[t] = o;
            }
            __syncthreads();
        }
        if (t == 0) {
            uint64_t m = red[0];
            if (m == 0) sh_r = 0;                // nothing fits -> done
            else {
                uint32_t pix = 65535u - (uint32_t)(m & 0xFFFFu);
                uint32_t k   = (uint32_t)(m >> 16);
                uint32_t c   = costOf(gb[pix]);
                selx[(size_t)b * HW + pix] = 1;
                sh_r -= c;
                sh_poskey = k; sh_pospix = pix;
            }
        }
        __syncthreads();
    }
}

// K3: masked sparse BEV + sel_idx output (c==0 blocks), float4-vectorized.
// sel recomputed inline from key/g/selx/hl (all L2-resident) — no selOut round-trip.
__global__ void k_sparse(const float* __restrict__ collab, const uint4* __restrict__ key4,
                         const uint32_t* __restrict__ g4, const uint32_t* __restrict__ selx4,
                         const uint32_t* __restrict__ hl_arr,
                         float* __restrict__ out, float* __restrict__ selOut) {
    int tid = blockIdx.x * blockDim.x + threadIdx.x;   // [0, HW/4)
    int c = blockIdx.y, b = blockIdx.z;
    int cls = (c < C_V) ? 0 : ((c < C_V + C_F) ? 1 : 2);
    uint32_t hl = hl_arr[b];                           // >= 1 always
    size_t p4 = (size_t)b * (HW / 4) + (size_t)tid;
    uint4 kk = key4[p4];
    uint32_t gg = g4[p4];
    uint32_t sx = selx4[p4];
    int sc[4];
    uint32_t kv[4] = { kk.x, kk.y, kk.z, kk.w };
    #pragma unroll
    for (int p = 0; p < 4; ++p) {
        bool se = (kv[p] >= hl) || (((sx >> (8 * p)) & 0xFFu) != 0u);
        sc[p] = se ? (int)((gg >> (8 * p)) & 3u) : -1;
    }
    size_t co = ((size_t)(b * C_ALL + c)) * HW + (size_t)tid * 4;
    float4 v = *(const float4*)(collab + co);
    float4 o;
    o.x = (sc[0] == cls) ? v.x : 0.0f;
    o.y = (sc[1] == cls) ? v.y : 0.0f;
    o.z = (sc[2] == cls) ? v.z : 0.0f;
    o.w = (sc[3] == cls) ? v.w : 0.0f;
    *(float4*)(out + co) = o;
    if (c == 0) {
        float4 sf = make_float4((float)sc[0], (float)sc[1], (float)sc[2], (float)sc[3]);
        ((float4*)selOut)[p4] = sf;
    }
}

extern "C" void kernel_launch(void* const* d_in, const int* in_sizes, int n_in,
                              void* d_out, int out_size, void* d_ws, size_t ws_size,
                              hipStream_t stream) {
    (void)in_sizes; (void)n_in; (void)out_size; (void)ws_size;
    const float* collab = (const float*)d_in[0];
    const float* util   = (const float*)d_in[1];
    const int*   budget = (const int*)d_in[2];

    uint8_t*  ws   = (uint8_t*)d_ws;
    uint32_t* hist = (uint32_t*)(ws + OFF_HIST);
    uint32_t* key  = (uint32_t*)(ws + OFF_KEY);
    uint8_t*  g    = ws + OFF_G;
    uint8_t*  selx = ws + OFF_SELX;
    uint32_t* hl   = (uint32_t*)(ws + OFF_HL);

    float* outSparse = (float*)d_out;
    float* outSel    = outSparse + (size_t)B_ * C_ALL * HW;

    k_zero  <<<(4 * HBINS / 4) / 256, 256, 0, stream>>>((uint4*)hist);
    k_prep  <<<(NPIX / 4 + 255) / 256, 256, 0, stream>>>(util, (uint4*)key,
                                                         (uint32_t*)g, (uint32_t*)selx, hist);
    k_select<<<B_, 1024, 0, stream>>>(key, g, hist, budget, selx, hl);
    dim3 grid3(HW / 4 / 256, C_ALL, B_);
    k_sparse<<<grid3, 256, 0, stream>>>(collab, (const uint4*)key, (const uint32_t*)g,
                                        (const uint32_t*)selx, hl, outSparse, outSel);
}